// Round 2
// baseline (74.800 us; speedup 1.0000x reference)
//
#include <hip/hip_runtime.h>
#include <hip/hip_bf16.h>
#include <math.h>

// Fully-fused: out = log_softmax((x@U) @ (mu@V)^T, axis=-1)
//   x [32,128] f32, mu [10,128] f32, U [128,512] f32, V [128,512] f32
// One block per batch row b (32 blocks x 512 threads). Thread t owns k=t:
//   fac1[t]    = sum_d x[b,d]*U[d,t]        (x[b,d] block-uniform -> s_load)
//   fac2[c][t] = sum_d mu[c,d]*V[d,t]       (V[d,t] loaded once, reused 10x;
//                                            mu[c,d] block-uniform -> s_load)
//   h[b,c]     = sum_t fac1[t]*fac2[c][t]   (butterfly + LDS cross-wave reduce)
// No workspace: d_ws untouched (the 256MB ws re-poison fill dominated R1's 65us).
#define BB 32
#define DD 128
#define KK 512
#define CC 10

__global__ __launch_bounds__(KK, 1) void fused_kernel(
    const float* __restrict__ x, const float* __restrict__ mu,
    const float* __restrict__ U, const float* __restrict__ V,
    float* __restrict__ out)
{
    const int b    = blockIdx.x;      // 0..31
    const int t    = threadIdx.x;     // 0..511 == k index
    const int lane = t & 63;
    const int wave = t >> 6;          // 0..7

    __shared__ float part[8][CC + 1];

    const float* __restrict__ xb = x + b * DD;

    float f1 = 0.0f;
    float acc[CC];
    #pragma unroll
    for (int c = 0; c < CC; ++c) acc[c] = 0.0f;

    // d-loop: 2 coalesced VMEM loads (U,V) + 11 FMA per iter; x/mu scalarize.
    #pragma unroll 4
    for (int d = 0; d < DD; ++d) {
        const float u = U[d * KK + t];
        const float v = V[d * KK + t];
        f1 = fmaf(xb[d], u, f1);
        #pragma unroll
        for (int c = 0; c < CC; ++c)
            acc[c] = fmaf(mu[c * DD + d], v, acc[c]);
    }

    // Per-thread contribution p[c] = fac1[t] * fac2[c][t]; wave butterfly,
    // then lane0 of each wave deposits its partial in LDS.
    #pragma unroll
    for (int c = 0; c < CC; ++c) {
        float s = f1 * acc[c];
        #pragma unroll
        for (int off = 32; off > 0; off >>= 1)
            s += __shfl_xor(s, off);
        if (lane == 0) part[wave][c] = s;
    }
    __syncthreads();

    if (wave == 0) {
        // Every lane of wave 0 sums the 8 wave-partials per c (uniform-address
        // LDS broadcasts, conflict-free), then computes log-softmax redundantly.
        float h[CC];
        #pragma unroll
        for (int c = 0; c < CC; ++c) {
            float s = 0.0f;
            #pragma unroll
            for (int w = 0; w < 8; ++w) s += part[w][c];
            h[c] = s;
        }
        float mx = h[0];
        #pragma unroll
        for (int c = 1; c < CC; ++c) mx = fmaxf(mx, h[c]);
        float sum = 0.0f;
        #pragma unroll
        for (int c = 0; c < CC; ++c) sum += __expf(h[c] - mx);
        const float lse = mx + __logf(sum);

        if (lane < CC) {
            // register-select h[lane] without dynamic indexing (no scratch)
            float v = h[0];
            #pragma unroll
            for (int c = 1; c < CC; ++c) v = (lane == c) ? h[c] : v;
            out[b * CC + lane] = v - lse;
        }
    }
}

extern "C" void kernel_launch(void* const* d_in, const int* in_sizes, int n_in,
                              void* d_out, int out_size, void* d_ws, size_t ws_size,
                              hipStream_t stream)
{
    const float* x  = (const float*)d_in[0];   // [32,128]
    const float* mu = (const float*)d_in[1];   // [10,128]
    const float* U  = (const float*)d_in[2];   // [128,512]
    const float* V  = (const float*)d_in[3];   // [128,512]
    float* out = (float*)d_out;                // [32,10]
    (void)d_ws; (void)ws_size;                 // deliberately unused

    fused_kernel<<<BB, KK, 0, stream>>>(x, mu, U, V, out);
}

// Round 3
// 63.833 us; speedup vs baseline: 1.1718x; 1.1718x over previous
//
#include <hip/hip_runtime.h>
#include <hip/hip_bf16.h>
#include <math.h>

// Two-kernel split (R1 structure, tuned):
//   fac[r][k], r in [0,42): r<32 -> x_row r @ U ; else mu_row (r-32) @ V
//   then h = fac1 @ fac2^T + row log-softmax in a 1-wave-per-row kernel.
// The 256MB ws re-poison fill (~40us @85% HBM) is an unconditional harness
// cost (verified R2: fill present with ws unused) — only the kernel slice
// (~3-5us of the ~65us total) is controllable.
#define BB 32
#define DD 128
#define KK 512
#define CC 10
#define KSPLIT 4
#define KCH (KK / KSPLIT)   // 128 threads per block in kernel A

__global__ __launch_bounds__(KCH) void fac_kernel(
    const float* __restrict__ x, const float* __restrict__ mu,
    const float* __restrict__ U, const float* __restrict__ V,
    float* __restrict__ fac)
{
    const int r  = blockIdx.x;            // 0..41
    const int ks = blockIdx.y;            // 0..KSPLIT-1
    const int k  = ks * KCH + threadIdx.x;

    const float* __restrict__ row = (r < BB) ? (x + r * DD) : (mu + (r - BB) * DD);
    const float* __restrict__ W   = (r < BB) ? U : V;

    // Two interleaved accumulator chains; unroll 32 keeps 32 independent
    // coalesced loads in flight per group (4 latency groups over D=128).
    float acc0 = 0.0f, acc1 = 0.0f;
    #pragma unroll 16
    for (int d = 0; d < DD; d += 2) {
        acc0 = fmaf(row[d],     W[d * KK + k],       acc0);
        acc1 = fmaf(row[d + 1], W[(d + 1) * KK + k], acc1);
    }
    fac[r * KK + k] = acc0 + acc1;
}

// One block (1 wave) per batch row: lane owns 8 consecutive k of fac1,
// dots against the 10 fac2 rows, butterfly-reduces, log-softmax in-wave.
__global__ __launch_bounds__(64) void h_softmax_kernel(
    const float* __restrict__ fac, float* __restrict__ out)
{
    const int b    = blockIdx.x;      // 0..31
    const int lane = threadIdx.x;     // 0..63

    const float* __restrict__ f1 = fac + b * KK;
    const float* __restrict__ f2 = fac + BB * KK;   // fac2 base [10][512]

    const float4* f1v = (const float4*)(f1 + lane * 8);
    const float4 p0 = f1v[0];
    const float4 p1 = f1v[1];

    float hrow[CC];
    #pragma unroll
    for (int c = 0; c < CC; ++c) {
        const float4* f2v = (const float4*)(f2 + c * KK + lane * 8);
        const float4 q0 = f2v[0];
        const float4 q1 = f2v[1];
        float s = p0.x * q0.x + p0.y * q0.y + p0.z * q0.z + p0.w * q0.w
                + p1.x * q1.x + p1.y * q1.y + p1.z * q1.z + p1.w * q1.w;
        #pragma unroll
        for (int off = 32; off > 0; off >>= 1)
            s += __shfl_xor(s, off);
        hrow[c] = s;
    }

    float mx = hrow[0];
    #pragma unroll
    for (int c = 1; c < CC; ++c) mx = fmaxf(mx, hrow[c]);
    float sum = 0.0f;
    #pragma unroll
    for (int c = 0; c < CC; ++c) sum += __expf(hrow[c] - mx);
    const float lse = mx + __logf(sum);

    if (lane < CC) {
        float v = hrow[0];
        #pragma unroll
        for (int c = 1; c < CC; ++c) v = (lane == c) ? hrow[c] : v;
        out[b * CC + lane] = v - lse;
    }
}

extern "C" void kernel_launch(void* const* d_in, const int* in_sizes, int n_in,
                              void* d_out, int out_size, void* d_ws, size_t ws_size,
                              hipStream_t stream)
{
    const float* x  = (const float*)d_in[0];   // [32,128]
    const float* mu = (const float*)d_in[1];   // [10,128]
    const float* U  = (const float*)d_in[2];   // [128,512]
    const float* V  = (const float*)d_in[3];   // [128,512]
    float* out = (float*)d_out;                // [32,10]
    float* fac = (float*)d_ws;                 // [42,512] scratch (86 KB)

    dim3 gridA(BB + CC, KSPLIT);               // 42 x 4 = 168 blocks
    fac_kernel<<<gridA, KCH, 0, stream>>>(x, mu, U, V, fac);
    h_softmax_kernel<<<BB, 64, 0, stream>>>(fac, out);
}